// Round 1
// baseline (739.718 us; speedup 1.0000x reference)
//
#include <hip/hip_runtime.h>
#include <cstdint>
#include <cstddef>

typedef __bf16  bf16x8  __attribute__((ext_vector_type(8)));
typedef short   shortx8 __attribute__((ext_vector_type(8)));
typedef float   f32x4   __attribute__((ext_vector_type(4)));

constexpr int P_PARTS     = 62;
constexpr int N_TOK       = 8192;
constexpr int C_IN        = 128;
constexpr int C_OUT       = 256;
constexpr int ROWS_PER_WG = 512;                       // rows per block
constexpr int ROWS_ITER   = 64;                        // rows per K-tile iteration
constexpr int N_ITER      = ROWS_PER_WG / ROWS_ITER;   // 8
constexpr int WG_PER_PART = N_TOK / ROWS_PER_WG;       // 16
constexpr int XSTRIDE     = C_IN + 8;                  // bf16 elems; +8 pad -> ~2-way LDS aliasing (free)
constexpr float LN_EPS    = 1e-5f;

__device__ __forceinline__ short f2bf_rne(float f) {
    uint32_t u = __float_as_uint(f);
    u += 0x7FFFu + ((u >> 16) & 1u);     // round-to-nearest-even to bf16
    return (short)(u >> 16);
}

union FragU { shortx8 s; bf16x8 b; };

__device__ __forceinline__ bf16x8 cvt8(f32x4 a, f32x4 b) {
    FragU fu;
    fu.s[0] = f2bf_rne(a[0]); fu.s[1] = f2bf_rne(a[1]);
    fu.s[2] = f2bf_rne(a[2]); fu.s[3] = f2bf_rne(a[3]);
    fu.s[4] = f2bf_rne(b[0]); fu.s[5] = f2bf_rne(b[1]);
    fu.s[6] = f2bf_rne(b[2]); fu.s[7] = f2bf_rne(b[3]);
    return fu.b;
}

// Fused per-part FC (x[P,N,128] @ W[P,256,128]^T) + LayerNorm(256), all in one pass.
// Memory-bound: x read once, out written once, W held in registers per block.
extern "C" __global__ void __launch_bounds__(256, 3)
fused_fc_ln(const float* __restrict__ x, const float* __restrict__ Wt,
            const float* __restrict__ gamma, const float* __restrict__ beta,
            float* __restrict__ out)
{
    __shared__ __align__(16) short xs[ROWS_ITER * XSTRIDE];  // 17408 B bf16 x-tile
    __shared__ float psum[ROWS_ITER][4];
    __shared__ float psq [ROWS_ITER][4];
    __shared__ float rmean[ROWS_ITER];
    __shared__ float rrstd[ROWS_ITER];

    const int tid  = threadIdx.x;
    const int wv   = tid >> 6;       // wave 0..3 -> owns cols [wv*64, wv*64+64)
    const int lane = tid & 63;
    const int quad = lane >> 4;      // 0..3
    const int l16  = lane & 15;

    const int part = blockIdx.x >> 4;    // WG_PER_PART == 16
    const int rb   = blockIdx.x & 15;
    const long rowBase = (long)part * N_TOK + (long)rb * ROWS_PER_WG;

    // ---- W fragments for this wave's 64 channels: fp32 -> bf16, kept in VGPRs ----
    // B-operand layout: n = lane&15, k = quad*8 + j  (j = element in frag)
    bf16x8 bfrag[4][4];              // [colTile][kChunk]
    float g[4], bt[4];
    #pragma unroll
    for (int ct = 0; ct < 4; ++ct) {
        const int d = wv * 64 + ct * 16 + l16;
        g[ct]  = gamma[d];
        bt[ct] = beta[d];
        const float* wp = Wt + ((size_t)part * C_OUT + d) * C_IN + quad * 8;
        #pragma unroll
        for (int kk = 0; kk < 4; ++kk) {
            const f32x4* p4 = (const f32x4*)(wp + kk * 32);
            bfrag[ct][kk] = cvt8(p4[0], p4[1]);
        }
    }

    const float* xblk = x   + rowBase * C_IN;
    float*       oblk = out + rowBase * C_OUT;

    for (int it = 0; it < N_ITER; ++it) {
        // ---- stage 64x128 fp32 x-tile -> bf16 LDS (tile is contiguous 32 KB) ----
        const float* xsrc = xblk + (size_t)it * (ROWS_ITER * C_IN);
        #pragma unroll
        for (int i = 0; i < 4; ++i) {
            const int c  = tid + i * 256;          // 16B-bf16 chunk id, 1024 total
            const int r  = c >> 4;                 // row (16 chunks per row)
            const int ck = c & 15;
            const f32x4* p4 = (const f32x4*)(xsrc + (size_t)c * 8);
            FragU fu; fu.b = cvt8(p4[0], p4[1]);
            *(shortx8*)&xs[r * XSTRIDE + ck * 8] = fu.s;
        }
        __syncthreads();

        // ---- MFMA: 64 rows x 64 cols per wave, K = 128 ----
        f32x4 acc[4][4];                           // [rowTile][colTile]
        #pragma unroll
        for (int rt = 0; rt < 4; ++rt)
            #pragma unroll
            for (int ct = 0; ct < 4; ++ct)
                acc[rt][ct] = f32x4{0.f, 0.f, 0.f, 0.f};

        #pragma unroll
        for (int rt = 0; rt < 4; ++rt) {
            const int row = rt * 16 + l16;         // A-operand: m = lane&15
            bf16x8 af[4];
            #pragma unroll
            for (int kk = 0; kk < 4; ++kk)
                af[kk] = *(const bf16x8*)&xs[row * XSTRIDE + (kk * 4 + quad) * 8];
            #pragma unroll
            for (int ct = 0; ct < 4; ++ct)
                #pragma unroll
                for (int kk = 0; kk < 4; ++kk)
                    acc[rt][ct] = __builtin_amdgcn_mfma_f32_16x16x32_bf16(
                        af[kk], bfrag[ct][kk], acc[rt][ct], 0, 0, 0);
        }

        // ---- LN partial stats: this wave's 64-channel partial per row ----
        // C/D layout: col = lane&15, row = quad*4 + reg
        #pragma unroll
        for (int rt = 0; rt < 4; ++rt) {
            #pragma unroll
            for (int rg = 0; rg < 4; ++rg) {
                float a0 = acc[rt][0][rg], a1 = acc[rt][1][rg];
                float a2 = acc[rt][2][rg], a3 = acc[rt][3][rg];
                float s  = a0 + a1 + a2 + a3;
                float s2 = a0*a0 + a1*a1 + a2*a2 + a3*a3;
                #pragma unroll
                for (int off = 1; off < 16; off <<= 1) {
                    s  += __shfl_xor(s,  off, 64);
                    s2 += __shfl_xor(s2, off, 64);
                }
                if (l16 == 0) {
                    const int row = rt * 16 + quad * 4 + rg;
                    psum[row][wv] = s;
                    psq [row][wv] = s2;
                }
            }
        }
        __syncthreads();

        if (tid < ROWS_ITER) {
            const float s   = psum[tid][0] + psum[tid][1] + psum[tid][2] + psum[tid][3];
            const float q   = psq [tid][0] + psq [tid][1] + psq [tid][2] + psq [tid][3];
            const float mu  = s * (1.0f / C_OUT);
            const float var = q * (1.0f / C_OUT) - mu * mu;
            rmean[tid] = mu;
            rrstd[tid] = rsqrtf(var + LN_EPS);
        }
        __syncthreads();

        // ---- normalize + store (quad writes 64B contiguous per instruction) ----
        float* od = oblk + (size_t)it * (ROWS_ITER * C_OUT);
        #pragma unroll
        for (int rt = 0; rt < 4; ++rt) {
            #pragma unroll
            for (int rg = 0; rg < 4; ++rg) {
                const int row = rt * 16 + quad * 4 + rg;
                const float mu = rmean[row];
                const float rs = rrstd[row];
                float* orow = od + (size_t)row * C_OUT + wv * 64 + l16;
                #pragma unroll
                for (int ct = 0; ct < 4; ++ct)
                    orow[ct * 16] = (acc[rt][ct][rg] - mu) * rs * g[ct] + bt[ct];
            }
        }
        // no trailing barrier needed: all xs reads complete before the psum
        // barrier; next iter's psum/rmean writes are ordered by the barriers too.
    }
}

extern "C" void kernel_launch(void* const* d_in, const int* in_sizes, int n_in,
                              void* d_out, int out_size, void* d_ws, size_t ws_size,
                              hipStream_t stream) {
    const float* x     = (const float*)d_in[0];
    const float* Wt    = (const float*)d_in[1];
    const float* gamma = (const float*)d_in[2];
    const float* beta  = (const float*)d_in[3];
    float* out = (float*)d_out;
    (void)in_sizes; (void)n_in; (void)d_ws; (void)ws_size; (void)out_size;
    fused_fc_ln<<<dim3(P_PARTS * WG_PER_PART), dim3(256), 0, stream>>>(
        x, Wt, gamma, beta, out);
}